// Round 17
// baseline (133.385 us; speedup 1.0000x reference)
//
#include <hip/hip_runtime.h>
#include <hip/hip_bf16.h>

// ---------------------------------------------------------------------------
// LearnedMeans: 2-NN distances + statistics. R17 = R13's proven counted-vmcnt
// schedule scaled to a 128x256 / 8-wave / BK=64 block:
//   - per wave: 64x64 output (R14-verified acc[4][4] fragments + epilogue);
//     16 ds_reads feed 32 MFMAs per K-step (2.7x R13 ratio, 4x MFMA per
//     barrier interval -- attacks the per-step sync/issue floor that was
//     invariant across R8-R16).
//   - LDS 2 x (A 16KB + B 32KB) = 96KB -> 1 block/CU, 8 waves (2/SIMD).
//   - staging: 6 global_load_lds per thread per K-tile (A 2 sweeps + B 4
//     sweeps; R13-verified swizzle both-sides), 2-deep vmcnt(6), raw
//     s_barrier, no vmcnt(0) in loop (R13 skeleton verbatim).
//   - grid 640 = 8 mblk x 80 nblk, XCD-remapped (640%8==0).
// Fallback to the verified R2 path if ws_size < ~24 MB.
// ---------------------------------------------------------------------------

#define DIM 512
#define M_Q 1024
#define P_TM 4096
#define P_XT 16384
#define P_ALL (P_TM + P_XT)          // 20480
#define NROWS_ALL (M_Q + P_ALL)      // 21504

#define BM 128
#define BN 256
#define BK 64
#define NSTEP (DIM / BK)             // 8
#define CHUNK 64
#define NCHUNK_TM (P_TM / CHUNK)     // 64
#define NCHUNK_TOT (P_ALL / CHUNK)   // 320
#define BIGF 3.402823466e38f

typedef __bf16 bf16x8 __attribute__((ext_vector_type(8)));
typedef float f32x4 __attribute__((ext_vector_type(4)));
typedef unsigned short u16x8 __attribute__((ext_vector_type(8)));

__device__ __forceinline__ unsigned short f2bf(float f) {
    unsigned int u = __float_as_uint(f);
    unsigned int r = (u + 0x7fffu + ((u >> 16) & 1u)) >> 16;
    return (unsigned short)r;
}

__device__ __forceinline__ void merge1(float v, float& d1, float& d2) {
    if (v < d1) { d2 = d1; d1 = v; }
    else if (v < d2) { d2 = v; }
}

__device__ __forceinline__ void top2_shfl16(float& d1, float& d2) {
    #pragma unroll
    for (int off = 1; off < 16; off <<= 1) {
        float o1 = __shfl_xor(d1, off);
        float o2 = __shfl_xor(d2, off);
        float n1 = fminf(d1, o1);
        float n2 = fminf(fmaxf(d1, o1), fminf(d2, o2));
        d1 = n1; d2 = n2;
    }
}

__device__ __forceinline__ void async_copy16(const void* g, void* l) {
    __builtin_amdgcn_global_load_lds(
        (const __attribute__((address_space(1))) void*)g,
        (__attribute__((address_space(3))) void*)l,
        16, 0, 0);
}

// ---------------------------------------------------------------------------
// Pass 1: f32 -> bf16 + squared norms. One wave per row (512 elems, 8/lane).
// ---------------------------------------------------------------------------
__global__ __launch_bounds__(256) void convert_norms_kernel(
    const float* __restrict__ Q, const float* __restrict__ TMat,
    const float* __restrict__ XT,
    unsigned short* __restrict__ Qb, unsigned short* __restrict__ Db,
    float* __restrict__ qn, float* __restrict__ dn)
{
    const int wid = threadIdx.x >> 6;
    const int lane = threadIdx.x & 63;
    const int row = blockIdx.x * 4 + wid;

    const float* src;
    unsigned short* dst;
    float* ndst;
    if (row < M_Q) {
        src = Q + (size_t)row * DIM; dst = Qb + (size_t)row * DIM; ndst = qn + row;
    } else {
        int r = row - M_Q;
        src = (row < M_Q + P_TM) ? (TMat + (size_t)r * DIM)
                                 : (XT + (size_t)(row - (M_Q + P_TM)) * DIM);
        dst = Db + (size_t)r * DIM; ndst = dn + r;
    }

    const float* p = src + lane * 8;
    float4 v0 = *(const float4*)p;
    float4 v1 = *(const float4*)(p + 4);
    float s = v0.x*v0.x + v0.y*v0.y + v0.z*v0.z + v0.w*v0.w
            + v1.x*v1.x + v1.y*v1.y + v1.z*v1.z + v1.w*v1.w;

    u16x8 o;
    o[0]=f2bf(v0.x); o[1]=f2bf(v0.y); o[2]=f2bf(v0.z); o[3]=f2bf(v0.w);
    o[4]=f2bf(v1.x); o[5]=f2bf(v1.y); o[6]=f2bf(v1.z); o[7]=f2bf(v1.w);
    *(u16x8*)(dst + lane * 8) = o;

    #pragma unroll
    for (int off = 32; off > 0; off >>= 1) s += __shfl_xor(s, off);
    if (lane == 0) *ndst = s;
}

// ---------------------------------------------------------------------------
// Pass 2: 128x256-tile, 8-wave MFMA distance + per-chunk top-2.
// Waves 2x4: wr = wid>>2 (M half), wc = wid&3 (N quarter = one 64-chunk).
// LDS per buffer: A[128][64] (16KB) + B[256][64] (32KB); 16B chunk c of row
// r stored at c^(r&7) (verified). Staging sweeps of 64 rows: thread ->
// row wid*8+(lane>>3), phys chunk lane&7, src chunk (lane&7)^((lane>>3)&7).
// Sync: R13 skeleton -- compute -> s_barrier -> stage(t+2, 6 copies) ->
// vmcnt(6) -> s_barrier. No vmcnt(0) in the main loop.
// ---------------------------------------------------------------------------
__global__ __launch_bounds__(512, 2) void dist_mfma_kernel(
    const unsigned short* __restrict__ Qb,   // [M_Q][DIM] bf16
    const unsigned short* __restrict__ Db,   // [P_ALL][DIM] bf16
    const float* __restrict__ qn,            // [M_Q]
    const float* __restrict__ dn,            // [P_ALL]
    float* __restrict__ partial)             // [M_Q][NCHUNK_TOT][2]
{
    __shared__ __align__(16) unsigned short As[2][BM * BK];  // 2 x 16 KB
    __shared__ __align__(16) unsigned short Bs[2][BN * BK];  // 2 x 32 KB

    const int tid  = threadIdx.x;        // 0..511
    const int lane = tid & 63;
    const int wid  = tid >> 6;           // 0..7
    const int wr   = wid >> 2;           // 0..1  (M half)
    const int wc   = wid & 3;            // 0..3  (N quarter)
    const int r15  = lane & 15;
    const int h    = lane >> 4;          // 0..3

    // --- XCD-aware remap: 640 blocks = 8 mblk x 80 nblk ---
    const int bid   = blockIdx.x;
    const int xcd   = bid & 7;
    const int j     = bid >> 3;          // 0..79
    const int mblk  = j & 7;
    const int nblk  = ((j >> 3) << 3) + xcd;   // 0..79
    const int mBase = mblk * BM;
    const int nBase = nblk * BN;

    // --- staging (verified R13 mapping): sweep covers 64 rows ---
    const int rowIn = wid * 8 + (lane >> 3);          // 0..63 within sweep
    const int clog  = (lane & 7) ^ ((lane >> 3) & 7); // inverse swizzle
    const unsigned short* srcA0 = Qb + (size_t)(mBase + rowIn) * DIM + clog * 8;
    const unsigned short* srcA1 = srcA0 + (size_t)64 * DIM;
    const unsigned short* srcB0 = Db + (size_t)(nBase + rowIn) * DIM + clog * 8;
    const unsigned short* srcB1 = srcB0 + (size_t)64 * DIM;
    const unsigned short* srcB2 = srcB0 + (size_t)128 * DIM;
    const unsigned short* srcB3 = srcB0 + (size_t)192 * DIM;
    const int ldsL = wid * 1024 + lane * 16;   // byte offset in 8KB sweep

    // --- ds_read addresses (ushort idx; verified R13/R14 conventions) ---
    int aA0[4], aA1[4], bB0[4], bB1[4];
    #pragma unroll
    for (int mi = 0; mi < 4; ++mi) {
        int rA = wr * 64 + mi * 16 + r15;
        aA0[mi] = rA * 64 + (((    h) ^ (rA & 7)) << 3);
        aA1[mi] = rA * 64 + (((4 | h) ^ (rA & 7)) << 3);
        int rB = wc * 64 + mi * 16 + r15;
        bB0[mi] = rB * 64 + (((    h) ^ (rB & 7)) << 3);
        bB1[mi] = rB * 64 + (((4 | h) ^ (rB & 7)) << 3);
    }

    f32x4 acc[4][4];
    #pragma unroll
    for (int mi = 0; mi < 4; ++mi)
        #pragma unroll
        for (int ni = 0; ni < 4; ++ni)
            #pragma unroll
            for (int i = 0; i < 4; ++i) acc[mi][ni][i] = 0.0f;

    // --- prologue: stage KT0 -> buf0, KT1 -> buf1 (6 copies each) ---
    async_copy16(srcA0,      (char*)&As[0][0]         + ldsL);
    async_copy16(srcA1,      (char*)&As[0][0] + 8192  + ldsL);
    async_copy16(srcB0,      (char*)&Bs[0][0]         + ldsL);
    async_copy16(srcB1,      (char*)&Bs[0][0] + 8192  + ldsL);
    async_copy16(srcB2,      (char*)&Bs[0][0] + 16384 + ldsL);
    async_copy16(srcB3,      (char*)&Bs[0][0] + 24576 + ldsL);
    async_copy16(srcA0 + BK, (char*)&As[1][0]         + ldsL);
    async_copy16(srcA1 + BK, (char*)&As[1][0] + 8192  + ldsL);
    async_copy16(srcB0 + BK, (char*)&Bs[1][0]         + ldsL);
    async_copy16(srcB1 + BK, (char*)&Bs[1][0] + 8192  + ldsL);
    async_copy16(srcB2 + BK, (char*)&Bs[1][0] + 16384 + ldsL);
    async_copy16(srcB3 + BK, (char*)&Bs[1][0] + 24576 + ldsL);
    asm volatile("s_waitcnt vmcnt(6)" ::: "memory");   // KT0 landed
    __builtin_amdgcn_sched_barrier(0);
    __builtin_amdgcn_s_barrier();
    __builtin_amdgcn_sched_barrier(0);

    #pragma unroll
    for (int t = 0; t < NSTEP; ++t) {
        const int cur = t & 1;

        // ---- compute step t from buf[cur]: 16 ds_reads, 32 MFMAs ----
        #pragma unroll
        for (int kh = 0; kh < 2; ++kh) {
            bf16x8 a0 = *(const bf16x8*)(&As[cur][kh ? aA1[0] : aA0[0]]);
            bf16x8 a1 = *(const bf16x8*)(&As[cur][kh ? aA1[1] : aA0[1]]);
            bf16x8 a2 = *(const bf16x8*)(&As[cur][kh ? aA1[2] : aA0[2]]);
            bf16x8 a3 = *(const bf16x8*)(&As[cur][kh ? aA1[3] : aA0[3]]);
            bf16x8 b0 = *(const bf16x8*)(&Bs[cur][kh ? bB1[0] : bB0[0]]);
            bf16x8 b1 = *(const bf16x8*)(&Bs[cur][kh ? bB1[1] : bB0[1]]);
            bf16x8 b2 = *(const bf16x8*)(&Bs[cur][kh ? bB1[2] : bB0[2]]);
            bf16x8 b3 = *(const bf16x8*)(&Bs[cur][kh ? bB1[3] : bB0[3]]);

            acc[0][0] = __builtin_amdgcn_mfma_f32_16x16x32_bf16(a0, b0, acc[0][0], 0, 0, 0);
            acc[0][1] = __builtin_amdgcn_mfma_f32_16x16x32_bf16(a0, b1, acc[0][1], 0, 0, 0);
            acc[0][2] = __builtin_amdgcn_mfma_f32_16x16x32_bf16(a0, b2, acc[0][2], 0, 0, 0);
            acc[0][3] = __builtin_amdgcn_mfma_f32_16x16x32_bf16(a0, b3, acc[0][3], 0, 0, 0);
            acc[1][0] = __builtin_amdgcn_mfma_f32_16x16x32_bf16(a1, b0, acc[1][0], 0, 0, 0);
            acc[1][1] = __builtin_amdgcn_mfma_f32_16x16x32_bf16(a1, b1, acc[1][1], 0, 0, 0);
            acc[1][2] = __builtin_amdgcn_mfma_f32_16x16x32_bf16(a1, b2, acc[1][2], 0, 0, 0);
            acc[1][3] = __builtin_amdgcn_mfma_f32_16x16x32_bf16(a1, b3, acc[1][3], 0, 0, 0);
            acc[2][0] = __builtin_amdgcn_mfma_f32_16x16x32_bf16(a2, b0, acc[2][0], 0, 0, 0);
            acc[2][1] = __builtin_amdgcn_mfma_f32_16x16x32_bf16(a2, b1, acc[2][1], 0, 0, 0);
            acc[2][2] = __builtin_amdgcn_mfma_f32_16x16x32_bf16(a2, b2, acc[2][2], 0, 0, 0);
            acc[2][3] = __builtin_amdgcn_mfma_f32_16x16x32_bf16(a2, b3, acc[2][3], 0, 0, 0);
            acc[3][0] = __builtin_amdgcn_mfma_f32_16x16x32_bf16(a3, b0, acc[3][0], 0, 0, 0);
            acc[3][1] = __builtin_amdgcn_mfma_f32_16x16x32_bf16(a3, b1, acc[3][1], 0, 0, 0);
            acc[3][2] = __builtin_amdgcn_mfma_f32_16x16x32_bf16(a3, b2, acc[3][2], 0, 0, 0);
            acc[3][3] = __builtin_amdgcn_mfma_f32_16x16x32_bf16(a3, b3, acc[3][3], 0, 0, 0);
        }

        __builtin_amdgcn_s_barrier();      // all waves done reading buf[cur]
        __builtin_amdgcn_sched_barrier(0);

        // ---- restage buf[cur] with KT(t+2); wait only for KT(t+1) ----
        if (t + 2 < NSTEP) {
            const int ks = (t + 2) * BK;
            async_copy16(srcA0 + ks, (char*)&As[cur][0]         + ldsL);
            async_copy16(srcA1 + ks, (char*)&As[cur][0] + 8192  + ldsL);
            async_copy16(srcB0 + ks, (char*)&Bs[cur][0]         + ldsL);
            async_copy16(srcB1 + ks, (char*)&Bs[cur][0] + 8192  + ldsL);
            async_copy16(srcB2 + ks, (char*)&Bs[cur][0] + 16384 + ldsL);
            async_copy16(srcB3 + ks, (char*)&Bs[cur][0] + 24576 + ldsL);
            asm volatile("s_waitcnt vmcnt(6)" ::: "memory");  // KT(t+1) landed
        } else if (t + 1 < NSTEP) {
            asm volatile("s_waitcnt vmcnt(0)" ::: "memory");  // tail
        }
        __builtin_amdgcn_sched_barrier(0);
        __builtin_amdgcn_s_barrier();      // buf[cur^1] ready for step t+1
        __builtin_amdgcn_sched_barrier(0);
    }

    // --- epilogue (R14-verified 4x4 conventions) ---
    float q2[4][4];
    #pragma unroll
    for (int mi = 0; mi < 4; ++mi)
        #pragma unroll
        for (int r = 0; r < 4; ++r)
            q2[mi][r] = qn[mBase + wr * 64 + mi * 16 + h * 4 + r];

    float d1[4][4], d2[4][4];
    #pragma unroll
    for (int mi = 0; mi < 4; ++mi)
        #pragma unroll
        for (int r = 0; r < 4; ++r) { d1[mi][r] = BIGF; d2[mi][r] = BIGF; }

    #pragma unroll
    for (int ni = 0; ni < 4; ++ni) {
        float dd = dn[nBase + wc * 64 + ni * 16 + r15];
        #pragma unroll
        for (int mi = 0; mi < 4; ++mi)
            #pragma unroll
            for (int r = 0; r < 4; ++r) {
                float sq = q2[mi][r] + dd - 2.0f * acc[mi][ni][r];
                sq = fmaxf(sq, 0.0f);
                merge1(sq, d1[mi][r], d2[mi][r]);
            }
    }

    #pragma unroll
    for (int mi = 0; mi < 4; ++mi)
        #pragma unroll
        for (int r = 0; r < 4; ++r)
            top2_shfl16(d1[mi][r], d2[mi][r]);

    if (r15 == 0) {
        const int chunkG = nblk * 4 + wc;
        #pragma unroll
        for (int mi = 0; mi < 4; ++mi)
            #pragma unroll
            for (int r = 0; r < 4; ++r) {
                int row = mBase + wr * 64 + mi * 16 + h * 4 + r;
                size_t base = ((size_t)row * NCHUNK_TOT + chunkG) * 2;
                partial[base]     = d1[mi][r];
                partial[base + 1] = d2[mi][r];
            }
    }
}

// ---------------------------------------------------------------------------
// Pass 3: merge per-chunk top-2 partials (one wave per query).
// ---------------------------------------------------------------------------
__global__ __launch_bounds__(256) void reduce_top2_kernel(
    const float* __restrict__ partial, float* __restrict__ fin)
{
    const int wid  = threadIdx.x >> 6;
    const int lane = threadIdx.x & 63;
    const int m = blockIdx.x * 4 + wid;
    const float* p = partial + (size_t)m * (NCHUNK_TOT * 2);

    float2 v = *(const float2*)(p + 2 * lane);
    float a1 = fminf(v.x, v.y), a2 = fmaxf(v.x, v.y);
    #pragma unroll
    for (int off = 32; off > 0; off >>= 1) {
        float o1 = __shfl_xor(a1, off);
        float o2 = __shfl_xor(a2, off);
        float n1 = fminf(a1, o1);
        float n2 = fminf(fmaxf(a1, o1), fminf(a2, o2));
        a1 = n1; a2 = n2;
    }

    const float* px = p + 2 * NCHUNK_TM + lane * 8;
    float4 w0 = *(const float4*)px;
    float4 w1 = *(const float4*)(px + 4);
    float b1 = BIGF, b2 = BIGF;
    merge1(w0.x, b1, b2); merge1(w0.y, b1, b2);
    merge1(w0.z, b1, b2); merge1(w0.w, b1, b2);
    merge1(w1.x, b1, b2); merge1(w1.y, b1, b2);
    merge1(w1.z, b1, b2); merge1(w1.w, b1, b2);
    #pragma unroll
    for (int off = 32; off > 0; off >>= 1) {
        float o1 = __shfl_xor(b1, off);
        float o2 = __shfl_xor(b2, off);
        float n1 = fminf(b1, o1);
        float n2 = fminf(fmaxf(b1, o1), fminf(b2, o2));
        b1 = n1; b2 = n2;
    }

    if (lane == 0) {
        fin[m]           = sqrtf(a1);
        fin[M_Q + m]     = sqrtf(a2);
        fin[2*M_Q + m]   = sqrtf(b1);
        fin[3*M_Q + m]   = sqrtf(b2);
    }
}

// ---------------------------------------------------------------------------
// Pass 4: stats. Both percentile arrays sorted in ONE bitonic pass.
// ---------------------------------------------------------------------------
__global__ __launch_bounds__(1024) void stats_kernel(
    const float* __restrict__ fin, float* __restrict__ out)
{
    __shared__ float s0[1024];
    __shared__ float s1a[1024];
    __shared__ float red[16][6];
    const int t = threadIdx.x;

    float m1 = fin[t];
    float m2 = fin[1024 + t];
    float s1 = fin[2048 + t];
    float s2 = fin[3072 + t];

    const float T = 1.0f / 3.0f;
    float v[6];
    v[0] = (m1 < T * s1 && m1 < T * m2) ? 1.0f : 0.0f;
    v[1] = (s1 < T * m1 && s1 < T * s2) ? 1.0f : 0.0f;
    v[2] = m1; v[3] = s1; v[4] = m2; v[5] = s2;

    #pragma unroll
    for (int off = 32; off > 0; off >>= 1)
        #pragma unroll
        for (int i = 0; i < 6; ++i) v[i] += __shfl_xor(v[i], off);

    int lane = t & 63, wid = t >> 6;
    if (lane == 0) {
        #pragma unroll
        for (int i = 0; i < 6; ++i) red[wid][i] = v[i];
    }
    __syncthreads();
    if (t == 0) {
        float a[6] = {0, 0, 0, 0, 0, 0};
        for (int w = 0; w < 16; ++w)
            for (int i = 0; i < 6; ++i) a[i] += red[w][i];
        out[0] = a[0];
        out[1] = a[1];
        out[2] = a[2] / 1024.0f;
        out[3] = a[3] / 1024.0f;
        out[4] = a[4] / 1024.0f;
        out[5] = a[5] / 1024.0f;
    }

    s0[t]  = m1;
    s1a[t] = s1;
    __syncthreads();

    for (int k = 2; k <= 1024; k <<= 1) {
        for (int jj = k >> 1; jj > 0; jj >>= 1) {
            int ixj = t ^ jj;
            if (ixj > t) {
                bool up = ((t & k) == 0);
                float a = s0[t], b = s0[ixj];
                if ((a > b) == up) { s0[t] = b; s0[ixj] = a; }
                float c = s1a[t], d = s1a[ixj];
                if ((c > d) == up) { s1a[t] = d; s1a[ixj] = c; }
            }
            __syncthreads();
        }
    }

    if (t < 5) {
        const float P[5] = {10.f, 25.f, 50.f, 75.f, 90.f};
        float q = P[t] * 1023.0f / 100.0f;
        int lo = (int)q;
        float fr = q - (float)lo;
        out[6 + t]  = s0[lo]  + fr * (s0[lo + 1]  - s0[lo]);
        out[11 + t] = s1a[lo] + fr * (s1a[lo + 1] - s1a[lo]);
    }
}

// ---------------------------------------------------------------------------
// Fallback path (verified R2 kernels) — used only if ws_size is too small.
// ---------------------------------------------------------------------------
__global__ __launch_bounds__(256) void norms_kernel_fb(
    const float* __restrict__ src, float* __restrict__ dst, int nrows)
{
    int wid = threadIdx.x >> 6;
    int lane = threadIdx.x & 63;
    int row = blockIdx.x * 4 + wid;
    if (row >= nrows) return;
    const float* p = src + (size_t)row * DIM + lane * 8;
    float4 v0 = *(const float4*)p;
    float4 v1 = *(const float4*)(p + 4);
    float s = v0.x*v0.x + v0.y*v0.y + v0.z*v0.z + v0.w*v0.w
            + v1.x*v1.x + v1.y*v1.y + v1.z*v1.z + v1.w*v1.w;
    #pragma unroll
    for (int off = 32; off > 0; off >>= 1) s += __shfl_xor(s, off);
    if (lane == 0) dst[row] = s;
}

__global__ __launch_bounds__(256) void dist_top2_kernel_fb(
    const float* __restrict__ Q, const float* __restrict__ Dset,
    const float* __restrict__ qn, const float* __restrict__ dn,
    float* __restrict__ partial, int chunkGlobalOffset)
{
    __shared__ __align__(16) unsigned short As[64][40];
    __shared__ __align__(16) unsigned short Bs[64][40];

    const int tid  = threadIdx.x;
    const int lane = tid & 63;
    const int wid  = tid >> 6;
    const int mBase = blockIdx.y * 64;
    const int nBase = blockIdx.x * 64;

    const int srow = tid >> 2;
    const int skc  = (tid & 3) * 8;

    const float* qrow = Q    + (size_t)(mBase + srow) * DIM + skc;
    const float* drow = Dset + (size_t)(nBase + srow) * DIM + skc;

    f32x4 acc[4];
    #pragma unroll
    for (int nt = 0; nt < 4; ++nt)
        #pragma unroll
        for (int i = 0; i < 4; ++i) acc[nt][i] = 0.0f;

    const int frow = lane & 15;
    const int fk   = (lane >> 4) * 8;

    for (int ks = 0; ks < DIM; ks += 32) {
        float4 a0 = *(const float4*)(qrow + ks);
        float4 a1 = *(const float4*)(qrow + ks + 4);
        float4 b0 = *(const float4*)(drow + ks);
        float4 b1 = *(const float4*)(drow + ks + 4);

        u16x8 va, vb;
        va[0]=f2bf(a0.x); va[1]=f2bf(a0.y); va[2]=f2bf(a0.z); va[3]=f2bf(a0.w);
        va[4]=f2bf(a1.x); va[5]=f2bf(a1.y); va[6]=f2bf(a1.z); va[7]=f2bf(a1.w);
        vb[0]=f2bf(b0.x); vb[1]=f2bf(b0.y); vb[2]=f2bf(b0.z); vb[3]=f2bf(b0.w);
        vb[4]=f2bf(b1.x); vb[5]=f2bf(b1.y); vb[6]=f2bf(b1.z); vb[7]=f2bf(b1.w);

        *(u16x8*)(&As[srow][skc]) = va;
        *(u16x8*)(&Bs[srow][skc]) = vb;
        __syncthreads();

        bf16x8 af = *(const bf16x8*)(&As[wid * 16 + frow][fk]);
        #pragma unroll
        for (int nt = 0; nt < 4; ++nt) {
            bf16x8 bf = *(const bf16x8*)(&Bs[nt * 16 + frow][fk]);
            acc[nt] = __builtin_amdgcn_mfma_f32_16x16x32_bf16(af, bf, acc[nt], 0, 0, 0);
        }
        __syncthreads();
    }

    const int rbase = mBase + wid * 16 + ((lane >> 4) << 2);
    float q2[4];
    #pragma unroll
    for (int r = 0; r < 4; ++r) q2[r] = qn[rbase + r];

    float d1[4], d2[4];
    #pragma unroll
    for (int r = 0; r < 4; ++r) { d1[r] = BIGF; d2[r] = BIGF; }

    #pragma unroll
    for (int nt = 0; nt < 4; ++nt) {
        float dd = dn[nBase + nt * 16 + (lane & 15)];
        #pragma unroll
        for (int r = 0; r < 4; ++r) {
            float sq = q2[r] + dd - 2.0f * acc[nt][r];
            sq = fmaxf(sq, 0.0f);
            merge1(sq, d1[r], d2[r]);
        }
    }

    #pragma unroll
    for (int r = 0; r < 4; ++r) top2_shfl16(d1[r], d2[r]);

    if ((lane & 15) == 0) {
        int chunkG = chunkGlobalOffset + blockIdx.x;
        #pragma unroll
        for (int r = 0; r < 4; ++r) {
            size_t base = ((size_t)(rbase + r) * NCHUNK_TOT + chunkG) * 2;
            partial[base]     = d1[r];
            partial[base + 1] = d2[r];
        }
    }
}

// ---------------------------------------------------------------------------
extern "C" void kernel_launch(void* const* d_in, const int* in_sizes, int n_in,
                              void* d_out, int out_size, void* d_ws, size_t ws_size,
                              hipStream_t stream) {
    const float* Q  = (const float*)d_in[0];
    const float* TM = (const float*)d_in[1];
    const float* XT = (const float*)d_in[2];
    float* out = (float*)d_out;

    const size_t needMain =
        (size_t)M_Q * DIM * 2 + (size_t)P_ALL * DIM * 2 +
        4 * ((size_t)M_Q + P_ALL + (size_t)M_Q * NCHUNK_TOT * 2 + 4 * M_Q);

    if (ws_size >= needMain) {
        char* w = (char*)d_ws;
        unsigned short* Qb = (unsigned short*)w;
        unsigned short* Db = (unsigned short*)(w + (size_t)M_Q * DIM * 2);
        float* qn = (float*)(w + (size_t)M_Q * DIM * 2 + (size_t)P_ALL * DIM * 2);
        float* dn = qn + M_Q;
        float* partial = dn + P_ALL;
        float* fin = partial + (size_t)M_Q * NCHUNK_TOT * 2;

        convert_norms_kernel<<<dim3(NROWS_ALL / 4), 256, 0, stream>>>(
            Q, TM, XT, Qb, Db, qn, dn);
        dist_mfma_kernel<<<dim3((M_Q / BM) * (P_ALL / BN)), 512, 0, stream>>>(
            Qb, Db, qn, dn, partial);
        reduce_top2_kernel<<<dim3(M_Q / 4), 256, 0, stream>>>(partial, fin);
        stats_kernel<<<dim3(1), 1024, 0, stream>>>(fin, out);
    } else {
        float* ws = (float*)d_ws;
        float* qn = ws;
        float* dn = ws + M_Q;
        float* partial = dn + P_ALL;
        float* fin = partial + (size_t)M_Q * NCHUNK_TOT * 2;

        norms_kernel_fb<<<dim3(M_Q / 4),  256, 0, stream>>>(Q,  qn, M_Q);
        norms_kernel_fb<<<dim3(P_TM / 4), 256, 0, stream>>>(TM, dn, P_TM);
        norms_kernel_fb<<<dim3(P_XT / 4), 256, 0, stream>>>(XT, dn + P_TM, P_XT);
        dist_top2_kernel_fb<<<dim3(P_TM / 64, M_Q / 64), 256, 0, stream>>>(
            Q, TM, qn, dn, partial, 0);
        dist_top2_kernel_fb<<<dim3(P_XT / 64, M_Q / 64), 256, 0, stream>>>(
            Q, XT, qn, dn + P_TM, partial, NCHUNK_TM);
        reduce_top2_kernel<<<dim3(M_Q / 4), 256, 0, stream>>>(partial, fin);
        stats_kernel<<<dim3(1), 1024, 0, stream>>>(fin, out);
    }
}